// Round 1
// baseline (362.841 us; speedup 1.0000x reference)
//
#include <hip/hip_runtime.h>
#include <stdint.h>

// ---------------- types ----------------
typedef short bf16x8 __attribute__((ext_vector_type(8)));
typedef float f32x4 __attribute__((ext_vector_type(4)));
typedef unsigned short u16x4 __attribute__((ext_vector_type(4)));
typedef unsigned short u16x8 __attribute__((ext_vector_type(8)));

#define MFMA16(a, b, c) __builtin_amdgcn_mfma_f32_16x16x32_bf16(a, b, c, 0, 0, 0)

// ---------------- workspace layout (byte offsets) ----------------
// ln buffers are dead after the QKV GEMM, so the attention outputs alias them.
static constexpr size_t LN_BYTES   = 8192ull * 512 * 2;       // bf16 [8192][512]
static constexpr size_t WQKV_BYTES = 1536ull * 512 * 2;       // bf16 [1536][512] (N x K)
static constexpr size_t WOUT_BYTES = 512ull * 512 * 2;        // bf16 [512][512]  (N x K)
static constexpr size_t QKV_BYTES  = 4ull * 8 * 2048 * 64 * 2;

static constexpr size_t OFF_LN0 = 0;
static constexpr size_t OFF_LN1 = OFF_LN0 + LN_BYTES;
static constexpr size_t OFF_WQ0 = OFF_LN1 + LN_BYTES;
static constexpr size_t OFF_WQ1 = OFF_WQ0 + WQKV_BYTES;
static constexpr size_t OFF_WO0 = OFF_WQ1 + WQKV_BYTES;
static constexpr size_t OFF_WO1 = OFF_WO0 + WOUT_BYTES;
static constexpr size_t OFF_Q0  = OFF_WO1 + WOUT_BYTES;   // [b][h][n][d], pre-scaled by 0.125
static constexpr size_t OFF_K0  = OFF_Q0 + QKV_BYTES;     // [b][h][n][d]
static constexpr size_t OFF_VT0 = OFF_K0 + QKV_BYTES;     // [b][h][d][n]  (V transposed)
static constexpr size_t OFF_Q1  = OFF_VT0 + QKV_BYTES;
static constexpr size_t OFF_K1  = OFF_Q1 + QKV_BYTES;
static constexpr size_t OFF_VT1 = OFF_K1 + QKV_BYTES;
static constexpr size_t OFF_AO0 = OFF_LN0;                // t2i attn out, merged heads [8192][512]
static constexpr size_t OFF_AO1 = OFF_LN1;                // i2t attn out

// ---------------- helpers ----------------
__device__ __forceinline__ unsigned short f2bf(float f) {
  union { float f; unsigned int u; } v; v.f = f;
  unsigned int r = v.u + 0x7FFFu + ((v.u >> 16) & 1u);
  return (unsigned short)(r >> 16);
}

__device__ __forceinline__ void gload16(const void* g, void* l) {
  __builtin_amdgcn_global_load_lds(
      (const __attribute__((address_space(1))) void*)g,
      (__attribute__((address_space(3))) void*)l, 16, 0, 0);
}

// ---------------- weight cast + transpose: w[K][N] f32 -> wt[N][K] bf16 ----------------
__global__ __launch_bounds__(256) void wt_kernel(const float* __restrict__ w,
                                                 unsigned short* __restrict__ wt,
                                                 int K, int N) {
  __shared__ float tile[64][65];
  int n0 = blockIdx.x * 64, k0 = blockIdx.y * 64;
  int t = threadIdx.x;
  int c = t & 63, rg = t >> 6;
#pragma unroll
  for (int i = 0; i < 16; i++) {
    int kk = i * 4 + rg;
    tile[kk][c] = w[(size_t)(k0 + kk) * N + n0 + c];
  }
  __syncthreads();
#pragma unroll
  for (int i = 0; i < 16; i++) {
    int nn = i * 4 + rg;
    wt[(size_t)(n0 + nn) * K + k0 + c] = f2bf(tile[c][nn]);
  }
}

// ---------------- layernorm (one wave per 512-wide row) ----------------
__global__ __launch_bounds__(256) void ln_kernel(
    const float* __restrict__ xi, const float* __restrict__ xt,
    const float* __restrict__ gi, const float* __restrict__ bi,
    const float* __restrict__ gt, const float* __restrict__ bt,
    char* __restrict__ ws) {
  int row = blockIdx.x * 4 + (threadIdx.x >> 6);
  int l = threadIdx.x & 63;
  const float *x, *g, *b; unsigned short* o; int r;
  if (row < 8192) { x = xi; g = gi; b = bi; o = (unsigned short*)(ws + OFF_LN0); r = row; }
  else            { x = xt; g = gt; b = bt; o = (unsigned short*)(ws + OFF_LN1); r = row - 8192; }
  const float4* xv = (const float4*)(x + (size_t)r * 512);
  float4 a0 = xv[l * 2], a1 = xv[l * 2 + 1];
  float s  = a0.x + a0.y + a0.z + a0.w + a1.x + a1.y + a1.z + a1.w;
  float ss = a0.x * a0.x + a0.y * a0.y + a0.z * a0.z + a0.w * a0.w +
             a1.x * a1.x + a1.y * a1.y + a1.z * a1.z + a1.w * a1.w;
#pragma unroll
  for (int m = 1; m < 64; m <<= 1) { s += __shfl_xor(s, m); ss += __shfl_xor(ss, m); }
  float mean = s * (1.0f / 512.0f);
  float var  = ss * (1.0f / 512.0f) - mean * mean;
  float rstd = rsqrtf(var + 1e-5f);
  const float4* gv = (const float4*)g;
  const float4* bv = (const float4*)b;
  float4 g0 = gv[l * 2], g1 = gv[l * 2 + 1], b0 = bv[l * 2], b1 = bv[l * 2 + 1];
  u16x8 ov;
  ov[0] = f2bf((a0.x - mean) * rstd * g0.x + b0.x);
  ov[1] = f2bf((a0.y - mean) * rstd * g0.y + b0.y);
  ov[2] = f2bf((a0.z - mean) * rstd * g0.z + b0.z);
  ov[3] = f2bf((a0.w - mean) * rstd * g0.w + b0.w);
  ov[4] = f2bf((a1.x - mean) * rstd * g1.x + b1.x);
  ov[5] = f2bf((a1.y - mean) * rstd * g1.y + b1.y);
  ov[6] = f2bf((a1.z - mean) * rstd * g1.z + b1.z);
  ov[7] = f2bf((a1.w - mean) * rstd * g1.w + b1.w);
  *(u16x8*)(o + (size_t)r * 512 + l * 8) = ov;
}

// ---------------- shared 128x128-tile GEMM core ----------------
// A: bf16 [M][512] row-major, B: bf16 [N][512] row-major (i.e. C = A * B^T).
// LDS tiles [128 rows][64 k] bf16, XOR-swizzled (chunk ^= row&7) via pre-swizzled
// global source (global_load_lds writes linearly: rule #21).
__device__ __forceinline__ void gemm128_core(const char* __restrict__ A,
                                             const char* __restrict__ B,
                                             int M0, int N0,
                                             char* lA, char* lB, f32x4 acc[4][4]) {
  int tid = threadIdx.x, w = tid >> 6, l = tid & 63;
  int wr = (w >> 1) * 64, wc = (w & 1) * 64;
  int l15 = l & 15, lg = l >> 4;
  int rl = l >> 3;
  int cswz = ((l & 7) ^ rl) << 4;
#pragma unroll 1
  for (int kt = 0; kt < 512; kt += 64) {
#pragma unroll
    for (int i = 0; i < 4; i++) {
      int rr = (w * 4 + i) * 8 + rl;
      gload16(A + (size_t)(M0 + rr) * 1024 + kt * 2 + cswz, lA + (w * 4 + i) * 1024);
      gload16(B + (size_t)(N0 + rr) * 1024 + kt * 2 + cswz, lB + (w * 4 + i) * 1024);
    }
    __syncthreads();
#pragma unroll
    for (int kk = 0; kk < 2; kk++) {
      bf16x8 af[4], bfv[4];
#pragma unroll
      for (int mi = 0; mi < 4; mi++) {
        int row = wr + mi * 16 + l15;
        af[mi] = *(const bf16x8*)(lA + row * 128 + ((kk * 64 + lg * 16) ^ ((row & 7) << 4)));
      }
#pragma unroll
      for (int ni = 0; ni < 4; ni++) {
        int row = wc + ni * 16 + l15;
        bfv[ni] = *(const bf16x8*)(lB + row * 128 + ((kk * 64 + lg * 16) ^ ((row & 7) << 4)));
      }
#pragma unroll
      for (int mi = 0; mi < 4; mi++)
#pragma unroll
        for (int ni = 0; ni < 4; ni++)
          acc[mi][ni] = MFMA16(af[mi], bfv[ni], acc[mi][ni]);
    }
    __syncthreads();
  }
}

// ---------------- QKV GEMM: ln[8192][512] @ wqkv -> q/k/vt buffers ----------------
__global__ __launch_bounds__(256, 2) void qkv_kernel(char* __restrict__ ws) {
  __shared__ char lA[16384];
  __shared__ char lB[16384];
  int s = blockIdx.z;
  const char* A = ws + (s ? OFF_LN1 : OFF_LN0);
  const char* B = ws + (s ? OFF_WQ1 : OFF_WQ0);
  unsigned short* qb = (unsigned short*)(ws + (s ? OFF_Q1 : OFF_Q0));
  unsigned short* kb = (unsigned short*)(ws + (s ? OFF_K1 : OFF_K0));
  unsigned short* vb = (unsigned short*)(ws + (s ? OFF_VT1 : OFF_VT0));
  int M0 = blockIdx.x * 128, N0 = blockIdx.y * 128;
  f32x4 zero = {0.f, 0.f, 0.f, 0.f};
  f32x4 acc[4][4];
#pragma unroll
  for (int mi = 0; mi < 4; mi++)
#pragma unroll
    for (int ni = 0; ni < 4; ni++) acc[mi][ni] = zero;
  gemm128_core(A, B, M0, N0, lA, lB, acc);

  int tid = threadIdx.x, w = tid >> 6, l = tid & 63;
  int wr = (w >> 1) * 64, wc = (w & 1) * 64;
  int l15 = l & 15, lg = l >> 4;
  int which = N0 >> 9;  // 0=q, 1=k, 2=v
#pragma unroll
  for (int mi = 0; mi < 4; mi++) {
    int m = M0 + wr + mi * 16 + lg * 4;
    int bb = m >> 11, t = m & 2047;
#pragma unroll
    for (int ni = 0; ni < 4; ni++) {
      int n = N0 + wc + ni * 16 + l15;
      int h = (n >> 6) & 7, d = n & 63;
      if (which == 2) {
        // vt[b][h][d][t] — 4 consecutive t per lane -> packed 8B store
        u16x4 pk;
        pk[0] = f2bf(acc[mi][ni][0]);
        pk[1] = f2bf(acc[mi][ni][1]);
        pk[2] = f2bf(acc[mi][ni][2]);
        pk[3] = f2bf(acc[mi][ni][3]);
        *(u16x4*)(vb + ((size_t)(bb * 8 + h) * 64 + d) * 2048 + t) = pk;
      } else {
        unsigned short* dst = (which ? kb : qb) + ((size_t)(bb * 8 + h) * 2048 + t) * 64 + d;
        float sc = which ? 1.0f : 0.125f;  // q pre-scaled (exact pow2 in bf16)
#pragma unroll
        for (int r = 0; r < 4; r++) dst[(size_t)r * 64] = f2bf(acc[mi][ni][r] * sc);
      }
    }
  }
}

// ---------------- flash cross-attention ----------------
// dir 0: t2i (q from t-stream, k/v from i-stream) -> AO0
// dir 1: i2t (q from i-stream, k/v from t-stream) -> AO1
__global__ __launch_bounds__(256, 2) void attn_kernel(char* __restrict__ ws) {
  __shared__ char lK[8192];   // [key 64][d 64] bf16, swizzled
  __shared__ char lV[8192];   // [d 64][key 64] bf16, swizzled
  __shared__ char lP[16384];  // per-wave [q 32][key 64] bf16, swizzled
  int dir = blockIdx.z;
  const unsigned short* qb = (const unsigned short*)(ws + (dir ? OFF_Q0 : OFF_Q1));
  const char* kbh;
  const char* vbh;
  {
    const char* kb = ws + (dir ? OFF_K1 : OFF_K0);
    const char* vb = ws + (dir ? OFF_VT1 : OFF_VT0);
    kbh = kb + (size_t)blockIdx.y * 2048 * 128;   // bytes: bh * 2048 * 64 * 2
    vbh = vb + (size_t)blockIdx.y * 2048 * 128;
  }
  unsigned short* ao = (unsigned short*)(ws + (dir ? OFF_AO1 : OFF_AO0));
  int bh = blockIdx.y;
  int q0 = blockIdx.x * 128;
  const unsigned short* qbh = qb + (size_t)bh * 2048 * 64;

  int tid = threadIdx.x, w = tid >> 6, l = tid & 63;
  int l15 = l & 15, lg = l >> 4;
  int rl = l >> 3;
  int cswz = ((l & 7) ^ rl) << 4;
  char* lPw = lP + w * 4096;

  // Q fragments (held in registers for all 32 k-tiles); q pre-scaled by 0.125
  bf16x8 qf[2][2];
#pragma unroll
  for (int qi = 0; qi < 2; qi++)
#pragma unroll
    for (int kk = 0; kk < 2; kk++) {
      int t = q0 + w * 32 + qi * 16 + l15;
      qf[qi][kk] = *(const bf16x8*)(qbh + (size_t)t * 64 + kk * 32 + lg * 8);
    }

  f32x4 zero = {0.f, 0.f, 0.f, 0.f};
  f32x4 oa[2][4];
  float mrun[2][4], lrun[2][4];
#pragma unroll
  for (int qi = 0; qi < 2; qi++) {
#pragma unroll
    for (int dj = 0; dj < 4; dj++) oa[qi][dj] = zero;
#pragma unroll
    for (int r = 0; r < 4; r++) { mrun[qi][r] = -3.0e38f; lrun[qi][r] = 0.f; }
  }

#pragma unroll 1
  for (int kt = 0; kt < 32; kt++) {
    // stage K tile [64][64] and Vt tile [64][64] (pre-swizzled global source)
#pragma unroll
    for (int i = 0; i < 2; i++) {
      int rr = (w * 2 + i) * 8 + rl;
      gload16(kbh + (size_t)(kt * 64 + rr) * 128 + cswz, lK + (w * 2 + i) * 1024);
      gload16(vbh + (size_t)rr * 4096 + kt * 128 + cswz, lV + (w * 2 + i) * 1024);
    }
    __syncthreads();

    // S = Q K^T  (S[q][key], rows q, cols key)
    f32x4 sa[2][4];
#pragma unroll
    for (int qi = 0; qi < 2; qi++)
#pragma unroll
      for (int kj = 0; kj < 4; kj++) sa[qi][kj] = zero;
#pragma unroll
    for (int kk = 0; kk < 2; kk++) {
      bf16x8 kf[4];
#pragma unroll
      for (int kj = 0; kj < 4; kj++) {
        int row = kj * 16 + l15;
        kf[kj] = *(const bf16x8*)(lK + row * 128 + ((kk * 64 + lg * 16) ^ ((row & 7) << 4)));
      }
#pragma unroll
      for (int qi = 0; qi < 2; qi++)
#pragma unroll
        for (int kj = 0; kj < 4; kj++)
          sa[qi][kj] = MFMA16(qf[qi][kk], kf[kj], sa[qi][kj]);
    }

    // online softmax: rows live on (lg, r); 16-lane butterfly over keys
#pragma unroll
    for (int qi = 0; qi < 2; qi++) {
#pragma unroll
      for (int r = 0; r < 4; r++) {
        float s0 = sa[qi][0][r], s1 = sa[qi][1][r], s2 = sa[qi][2][r], s3 = sa[qi][3][r];
        float mx = fmaxf(fmaxf(s0, s1), fmaxf(s2, s3));
#pragma unroll
        for (int msk = 1; msk < 16; msk <<= 1) mx = fmaxf(mx, __shfl_xor(mx, msk));
        float mn = fmaxf(mrun[qi][r], mx);
        float corr = __expf(mrun[qi][r] - mn);
        mrun[qi][r] = mn;
        float p0 = __expf(s0 - mn), p1 = __expf(s1 - mn);
        float p2 = __expf(s2 - mn), p3 = __expf(s3 - mn);
        float rs = p0 + p1 + p2 + p3;
#pragma unroll
        for (int msk = 1; msk < 16; msk <<= 1) rs += __shfl_xor(rs, msk);
        lrun[qi][r] = lrun[qi][r] * corr + rs;
#pragma unroll
        for (int dj = 0; dj < 4; dj++) oa[qi][dj][r] *= corr;
        // write P row to per-wave LDS (swizzled)
        int qrow = qi * 16 + lg * 4 + r;
        unsigned short* prow = (unsigned short*)(lPw + qrow * 128);
        int sz = (qrow & 7) << 4;
        prow[((l15 * 2) ^ sz) >> 1]          = f2bf(p0);
        prow[(((32 + l15 * 2)) ^ sz) >> 1]   = f2bf(p1);
        prow[(((64 + l15 * 2)) ^ sz) >> 1]   = f2bf(p2);
        prow[(((96 + l15 * 2)) ^ sz) >> 1]   = f2bf(p3);
      }
    }

    // O += P V   (A = P[q][key] from LDS, B = V via Vt[d][key] from LDS)
#pragma unroll
    for (int kk = 0; kk < 2; kk++) {
      bf16x8 pf[2], vf[4];
#pragma unroll
      for (int qi = 0; qi < 2; qi++) {
        int row = qi * 16 + l15;
        pf[qi] = *(const bf16x8*)(lPw + row * 128 + ((kk * 64 + lg * 16) ^ ((row & 7) << 4)));
      }
#pragma unroll
      for (int dj = 0; dj < 4; dj++) {
        int row = dj * 16 + l15;
        vf[dj] = *(const bf16x8*)(lV + row * 128 + ((kk * 64 + lg * 16) ^ ((row & 7) << 4)));
      }
#pragma unroll
      for (int qi = 0; qi < 2; qi++)
#pragma unroll
        for (int dj = 0; dj < 4; dj++)
          oa[qi][dj] = MFMA16(pf[qi], vf[dj], oa[qi][dj]);
    }
    __syncthreads();
  }

  // finalize + write merged-heads output ao[b][t][h*64+d]
  int b = bh >> 3, h = bh & 7;
#pragma unroll
  for (int qi = 0; qi < 2; qi++)
#pragma unroll
    for (int r = 0; r < 4; r++) {
      int t = q0 + w * 32 + qi * 16 + lg * 4 + r;
      float inv = 1.0f / lrun[qi][r];
#pragma unroll
      for (int dj = 0; dj < 4; dj++) {
        int col = h * 64 + dj * 16 + l15;
        ao[((size_t)b * 2048 + t) * 512 + col] = f2bf(oa[qi][dj][r] * inv);
      }
    }
}

// ---------------- output projection: ao[8192][512] @ w_out -> d_out (f32) ----------------
__global__ __launch_bounds__(256, 2) void proj_kernel(char* __restrict__ ws,
                                                      float* __restrict__ dout) {
  __shared__ char lA[16384];
  __shared__ char lB[16384];
  int dir = blockIdx.z;  // 0: t2i @ w_out_i -> rows [0,2048); 1: i2t @ w_out_t -> rows [2048,4096)
  const char* A = ws + (dir ? OFF_AO1 : OFF_AO0);
  const char* B = ws + (dir ? OFF_WO1 : OFF_WO0);
  int M0 = blockIdx.x * 128, N0 = blockIdx.y * 128;
  f32x4 zero = {0.f, 0.f, 0.f, 0.f};
  f32x4 acc[4][4];
#pragma unroll
  for (int mi = 0; mi < 4; mi++)
#pragma unroll
    for (int ni = 0; ni < 4; ni++) acc[mi][ni] = zero;
  gemm128_core(A, B, M0, N0, lA, lB, acc);

  int tid = threadIdx.x, w = tid >> 6, l = tid & 63;
  int wr = (w >> 1) * 64, wc = (w & 1) * 64;
  int l15 = l & 15, lg = l >> 4;
#pragma unroll
  for (int mi = 0; mi < 4; mi++) {
    int m = M0 + wr + mi * 16 + lg * 4;
    int bb = m >> 11, t = m & 2047;
    size_t orow = (size_t)bb * 4096 + (size_t)dir * 2048 + t;
#pragma unroll
    for (int ni = 0; ni < 4; ni++) {
      int n = N0 + wc + ni * 16 + l15;
#pragma unroll
      for (int r = 0; r < 4; r++) dout[(orow + r) * 512 + n] = acc[mi][ni][r];
    }
  }
}

// ---------------- launch ----------------
extern "C" void kernel_launch(void* const* d_in, const int* in_sizes, int n_in,
                              void* d_out, int out_size, void* d_ws, size_t ws_size,
                              hipStream_t stream) {
  const float* xi  = (const float*)d_in[0];
  const float* xt  = (const float*)d_in[1];
  const float* gi  = (const float*)d_in[2];
  const float* bi  = (const float*)d_in[3];
  const float* gt  = (const float*)d_in[4];
  const float* bt  = (const float*)d_in[5];
  const float* wqi = (const float*)d_in[6];
  const float* wqt = (const float*)d_in[7];
  const float* woi = (const float*)d_in[8];
  const float* wot = (const float*)d_in[9];
  char* ws = (char*)d_ws;
  float* out = (float*)d_out;

  wt_kernel<<<dim3(24, 8), 256, 0, stream>>>(wqi, (unsigned short*)(ws + OFF_WQ0), 512, 1536);
  wt_kernel<<<dim3(24, 8), 256, 0, stream>>>(wqt, (unsigned short*)(ws + OFF_WQ1), 512, 1536);
  wt_kernel<<<dim3(8, 8), 256, 0, stream>>>(woi, (unsigned short*)(ws + OFF_WO0), 512, 512);
  wt_kernel<<<dim3(8, 8), 256, 0, stream>>>(wot, (unsigned short*)(ws + OFF_WO1), 512, 512);
  ln_kernel<<<4096, 256, 0, stream>>>(xi, xt, gi, bi, gt, bt, ws);
  qkv_kernel<<<dim3(64, 12, 2), 256, 0, stream>>>(ws);
  attn_kernel<<<dim3(16, 32, 2), 256, 0, stream>>>(ws);
  proj_kernel<<<dim3(64, 4, 2), 256, 0, stream>>>(ws, out);
}

// Round 2
// 270.424 us; speedup vs baseline: 1.3417x; 1.3417x over previous
//
#include <hip/hip_runtime.h>
#include <stdint.h>

// ---------------- types ----------------
typedef short bf16x8 __attribute__((ext_vector_type(8)));
typedef float f32x4 __attribute__((ext_vector_type(4)));
typedef float f32x16 __attribute__((ext_vector_type(16)));
typedef unsigned short u16x4 __attribute__((ext_vector_type(4)));
typedef unsigned short u16x8 __attribute__((ext_vector_type(8)));
typedef unsigned int u32x4 __attribute__((ext_vector_type(4)));
typedef unsigned int u32;

#define MFMA16(a, b, c) __builtin_amdgcn_mfma_f32_16x16x32_bf16(a, b, c, 0, 0, 0)
#define MFMA32(a, b, c) __builtin_amdgcn_mfma_f32_32x32x16_bf16(a, b, c, 0, 0, 0)

// ---------------- workspace layout (byte offsets) ----------------
static constexpr size_t LN_BYTES   = 8192ull * 512 * 2;       // bf16 [8192][512]
static constexpr size_t WQKV_BYTES = 1536ull * 512 * 2;       // bf16 [1536][512] (N x K)
static constexpr size_t WOUT_BYTES = 512ull * 512 * 2;        // bf16 [512][512]  (N x K)
static constexpr size_t QKV_BYTES  = 4ull * 8 * 2048 * 64 * 2;

static constexpr size_t OFF_LN0 = 0;
static constexpr size_t OFF_LN1 = OFF_LN0 + LN_BYTES;
static constexpr size_t OFF_WQ0 = OFF_LN1 + LN_BYTES;
static constexpr size_t OFF_WQ1 = OFF_WQ0 + WQKV_BYTES;
static constexpr size_t OFF_WO0 = OFF_WQ1 + WQKV_BYTES;
static constexpr size_t OFF_WO1 = OFF_WO0 + WOUT_BYTES;
static constexpr size_t OFF_Q0  = OFF_WO1 + WOUT_BYTES;   // [b][h][n][d], pre-scaled by 0.125
static constexpr size_t OFF_K0  = OFF_Q0 + QKV_BYTES;     // [b][h][n][d]
static constexpr size_t OFF_VT0 = OFF_K0 + QKV_BYTES;     // [b][h][d][n]  (V transposed)
static constexpr size_t OFF_Q1  = OFF_VT0 + QKV_BYTES;
static constexpr size_t OFF_K1  = OFF_Q1 + QKV_BYTES;
static constexpr size_t OFF_VT1 = OFF_K1 + QKV_BYTES;
static constexpr size_t OFF_AO0 = OFF_LN0;                // t2i attn out, merged heads [8192][512]
static constexpr size_t OFF_AO1 = OFF_LN1;                // i2t attn out

// ---------------- helpers ----------------
__device__ __forceinline__ unsigned short f2bf(float f) {
  union { float f; unsigned int u; } v; v.f = f;
  unsigned int r = v.u + 0x7FFFu + ((v.u >> 16) & 1u);
  return (unsigned short)(r >> 16);
}

__device__ __forceinline__ void gload16(const void* g, void* l) {
  __builtin_amdgcn_global_load_lds(
      (const __attribute__((address_space(1))) void*)g,
      (__attribute__((address_space(3))) void*)l, 16, 0, 0);
}

__device__ __forceinline__ u32 cvtpk(float lo, float hi) {
  u32 d;
  asm("v_cvt_pk_bf16_f32 %0, %1, %2" : "=v"(d) : "v"(lo), "v"(hi));
  return d;
}

// (a,b) -> a' = {a.lo32lanes, b.lo32lanes}, b' = {a.hi32lanes, b.hi32lanes}
__device__ __forceinline__ void plswap(u32& a, u32& b) {
  asm("v_permlane32_swap_b32 %0, %1" : "+v"(a), "+v"(b));
}

__device__ __forceinline__ f32x16 zero16() {
  f32x16 z;
#pragma unroll
  for (int i = 0; i < 16; i++) z[i] = 0.0f;
  return z;
}

// ---------------- weight cast + transpose: w[K][N] f32 -> wt[N][K] bf16 ----------------
__global__ __launch_bounds__(256) void wt_kernel(const float* __restrict__ w,
                                                 unsigned short* __restrict__ wt,
                                                 int K, int N) {
  __shared__ float tile[64][65];
  int n0 = blockIdx.x * 64, k0 = blockIdx.y * 64;
  int t = threadIdx.x;
  int c = t & 63, rg = t >> 6;
#pragma unroll
  for (int i = 0; i < 16; i++) {
    int kk = i * 4 + rg;
    tile[kk][c] = w[(size_t)(k0 + kk) * N + n0 + c];
  }
  __syncthreads();
#pragma unroll
  for (int i = 0; i < 16; i++) {
    int nn = i * 4 + rg;
    wt[(size_t)(n0 + nn) * K + k0 + c] = f2bf(tile[c][nn]);
  }
}

// ---------------- layernorm (one wave per 512-wide row) ----------------
__global__ __launch_bounds__(256) void ln_kernel(
    const float* __restrict__ xi, const float* __restrict__ xt,
    const float* __restrict__ gi, const float* __restrict__ bi,
    const float* __restrict__ gt, const float* __restrict__ bt,
    char* __restrict__ ws) {
  int row = blockIdx.x * 4 + (threadIdx.x >> 6);
  int l = threadIdx.x & 63;
  const float *x, *g, *b; unsigned short* o; int r;
  if (row < 8192) { x = xi; g = gi; b = bi; o = (unsigned short*)(ws + OFF_LN0); r = row; }
  else            { x = xt; g = gt; b = bt; o = (unsigned short*)(ws + OFF_LN1); r = row - 8192; }
  const float4* xv = (const float4*)(x + (size_t)r * 512);
  float4 a0 = xv[l * 2], a1 = xv[l * 2 + 1];
  float s  = a0.x + a0.y + a0.z + a0.w + a1.x + a1.y + a1.z + a1.w;
  float ss = a0.x * a0.x + a0.y * a0.y + a0.z * a0.z + a0.w * a0.w +
             a1.x * a1.x + a1.y * a1.y + a1.z * a1.z + a1.w * a1.w;
#pragma unroll
  for (int m = 1; m < 64; m <<= 1) { s += __shfl_xor(s, m); ss += __shfl_xor(ss, m); }
  float mean = s * (1.0f / 512.0f);
  float var  = ss * (1.0f / 512.0f) - mean * mean;
  float rstd = rsqrtf(var + 1e-5f);
  const float4* gv = (const float4*)g;
  const float4* bv = (const float4*)b;
  float4 g0 = gv[l * 2], g1 = gv[l * 2 + 1], b0 = bv[l * 2], b1 = bv[l * 2 + 1];
  u16x8 ov;
  ov[0] = f2bf((a0.x - mean) * rstd * g0.x + b0.x);
  ov[1] = f2bf((a0.y - mean) * rstd * g0.y + b0.y);
  ov[2] = f2bf((a0.z - mean) * rstd * g0.z + b0.z);
  ov[3] = f2bf((a0.w - mean) * rstd * g0.w + b0.w);
  ov[4] = f2bf((a1.x - mean) * rstd * g1.x + b1.x);
  ov[5] = f2bf((a1.y - mean) * rstd * g1.y + b1.y);
  ov[6] = f2bf((a1.z - mean) * rstd * g1.z + b1.z);
  ov[7] = f2bf((a1.w - mean) * rstd * g1.w + b1.w);
  *(u16x8*)(o + (size_t)r * 512 + l * 8) = ov;
}

// ---------------- shared 128x128-tile GEMM core ----------------
__device__ __forceinline__ void gemm128_core(const char* __restrict__ A,
                                             const char* __restrict__ B,
                                             int M0, int N0,
                                             char* lA, char* lB, f32x4 acc[4][4]) {
  int tid = threadIdx.x, w = tid >> 6, l = tid & 63;
  int wr = (w >> 1) * 64, wc = (w & 1) * 64;
  int l15 = l & 15, lg = l >> 4;
  int rl = l >> 3;
  int cswz = ((l & 7) ^ rl) << 4;
#pragma unroll 1
  for (int kt = 0; kt < 512; kt += 64) {
#pragma unroll
    for (int i = 0; i < 4; i++) {
      int rr = (w * 4 + i) * 8 + rl;
      gload16(A + (size_t)(M0 + rr) * 1024 + kt * 2 + cswz, lA + (w * 4 + i) * 1024);
      gload16(B + (size_t)(N0 + rr) * 1024 + kt * 2 + cswz, lB + (w * 4 + i) * 1024);
    }
    __syncthreads();
#pragma unroll
    for (int kk = 0; kk < 2; kk++) {
      bf16x8 af[4], bfv[4];
#pragma unroll
      for (int mi = 0; mi < 4; mi++) {
        int row = wr + mi * 16 + l15;
        af[mi] = *(const bf16x8*)(lA + row * 128 + ((kk * 64 + lg * 16) ^ ((row & 7) << 4)));
      }
#pragma unroll
      for (int ni = 0; ni < 4; ni++) {
        int row = wc + ni * 16 + l15;
        bfv[ni] = *(const bf16x8*)(lB + row * 128 + ((kk * 64 + lg * 16) ^ ((row & 7) << 4)));
      }
#pragma unroll
      for (int mi = 0; mi < 4; mi++)
#pragma unroll
        for (int ni = 0; ni < 4; ni++)
          acc[mi][ni] = MFMA16(af[mi], bfv[ni], acc[mi][ni]);
    }
    __syncthreads();
  }
}

// ---------------- QKV GEMM: ln[8192][512] @ wqkv -> q/k/vt buffers ----------------
__global__ __launch_bounds__(256, 2) void qkv_kernel(char* __restrict__ ws) {
  __shared__ char lA[16384];
  __shared__ char lB[16384];
  int s = blockIdx.z;
  const char* A = ws + (s ? OFF_LN1 : OFF_LN0);
  const char* B = ws + (s ? OFF_WQ1 : OFF_WQ0);
  unsigned short* qb = (unsigned short*)(ws + (s ? OFF_Q1 : OFF_Q0));
  unsigned short* kb = (unsigned short*)(ws + (s ? OFF_K1 : OFF_K0));
  unsigned short* vb = (unsigned short*)(ws + (s ? OFF_VT1 : OFF_VT0));
  int M0 = blockIdx.x * 128, N0 = blockIdx.y * 128;
  f32x4 zero = {0.f, 0.f, 0.f, 0.f};
  f32x4 acc[4][4];
#pragma unroll
  for (int mi = 0; mi < 4; mi++)
#pragma unroll
    for (int ni = 0; ni < 4; ni++) acc[mi][ni] = zero;
  gemm128_core(A, B, M0, N0, lA, lB, acc);

  int tid = threadIdx.x, w = tid >> 6, l = tid & 63;
  int wr = (w >> 1) * 64, wc = (w & 1) * 64;
  int l15 = l & 15, lg = l >> 4;
  int which = N0 >> 9;  // 0=q, 1=k, 2=v
#pragma unroll
  for (int mi = 0; mi < 4; mi++) {
    int m = M0 + wr + mi * 16 + lg * 4;
    int bb = m >> 11, t = m & 2047;
#pragma unroll
    for (int ni = 0; ni < 4; ni++) {
      int n = N0 + wc + ni * 16 + l15;
      int h = (n >> 6) & 7, d = n & 63;
      if (which == 2) {
        u16x4 pk;
        pk[0] = f2bf(acc[mi][ni][0]);
        pk[1] = f2bf(acc[mi][ni][1]);
        pk[2] = f2bf(acc[mi][ni][2]);
        pk[3] = f2bf(acc[mi][ni][3]);
        *(u16x4*)(vb + ((size_t)(bb * 8 + h) * 64 + d) * 2048 + t) = pk;
      } else {
        unsigned short* dst = (which ? kb : qb) + ((size_t)(bb * 8 + h) * 2048 + t) * 64 + d;
        float sc = which ? 1.0f : 0.125f;  // q pre-scaled (exact pow2 in bf16)
#pragma unroll
        for (int r = 0; r < 4; r++) dst[(size_t)r * 64] = f2bf(acc[mi][ni][r] * sc);
      }
    }
  }
}

// ---------------- flash cross-attention, swapped-operand 32x32 (m214 structure) ----------------
// Each wave owns 32 q-rows (q = lane&31). S^T = mfma(K,Q) keeps a full q-row's
// scores lane-local; softmax is in-register; P->bf16 via cvt_pk + permlane32_swap;
// O^T = V^T P^T keeps q lane-local for rescale/finalize. No P LDS round-trip.
__global__ __launch_bounds__(256, 2) void attn_kernel(char* __restrict__ ws) {
  __shared__ char lK[2][8192];   // [key 64][d 64] bf16, XOR-swizzled
  __shared__ char lV[2][8192];   // [d 64][key 64] bf16, XOR-swizzled
  int dir = blockIdx.z;
  const char* kbh = ws + (dir ? OFF_K1 : OFF_K0) + (size_t)blockIdx.y * 2048 * 128;
  const char* vbh = ws + (dir ? OFF_VT1 : OFF_VT0) + (size_t)blockIdx.y * 2048 * 128;
  const char* qbh = ws + (dir ? OFF_Q0 : OFF_Q1) + (size_t)blockIdx.y * 2048 * 128;
  unsigned short* ao = (unsigned short*)(ws + (dir ? OFF_AO1 : OFF_AO0));
  int q0 = blockIdx.x * 128;

  int tid = threadIdx.x, w = tid >> 6, l = tid & 63;
  int l31 = l & 31, hi = l >> 5;
  int rl = l >> 3;
  int cswz = ((l & 7) ^ rl) << 4;
  int r7 = (l31 & 7) << 4;

  // Q fragments: qf[kc] = Q[q=qrow][d = 16*kc + 8*hi .. +7]  (pre-scaled by 0.125)
  int qrow = q0 + w * 32 + l31;
  bf16x8 qf[4];
#pragma unroll
  for (int kc = 0; kc < 4; kc++)
    qf[kc] = *(const bf16x8*)(qbh + (size_t)qrow * 128 + kc * 32 + hi * 16);

  f32x16 oA = zero16(), oB = zero16();
  float mrun = -3.0e38f, lrun = 0.f;

  // stage tile kt into buffer buf
#define STAGE(buf, kt)                                                              \
  {                                                                                 \
    _Pragma("unroll")                                                               \
    for (int i = 0; i < 2; i++) {                                                   \
      int rr = (w * 2 + i) * 8 + rl;                                                \
      gload16(kbh + (size_t)((kt) * 64 + rr) * 128 + cswz, &lK[buf][(w * 2 + i) * 1024]); \
      gload16(vbh + (size_t)rr * 4096 + (kt) * 128 + cswz, &lV[buf][(w * 2 + i) * 1024]); \
    }                                                                               \
  }

  STAGE(0, 0);
  __syncthreads();

  int cur = 0;
#pragma unroll 1
  for (int kt = 0; kt < 32; kt++) {
    if (kt < 31) STAGE(cur ^ 1, kt + 1);

    const char* K = lK[cur];
    const char* V = lV[cur];

    // ---- S^T = K Q^T : sA = keys 0..31, sB = keys 32..63 of this tile ----
    f32x16 sA = zero16(), sB = zero16();
    __builtin_amdgcn_s_setprio(1);
#pragma unroll
    for (int kc = 0; kc < 4; kc++) {
      bf16x8 kfA = *(const bf16x8*)(K + l31 * 128 + ((kc * 32 + hi * 16) ^ r7));
      bf16x8 kfB = *(const bf16x8*)(K + (32 + l31) * 128 + ((kc * 32 + hi * 16) ^ r7));
      sA = MFMA32(kfA, qf[kc], sA);
      sB = MFMA32(kfB, qf[kc], sB);
    }
    __builtin_amdgcn_s_setprio(0);

    // ---- online softmax (lane-local q-row; keys split across hi halves) ----
    float v8[8];
#pragma unroll
    for (int i = 0; i < 8; i++)
      v8[i] = fmaxf(fmaxf(sA[i], sA[i + 8]), fmaxf(sB[i], sB[i + 8]));
#pragma unroll
    for (int st = 4; st > 0; st >>= 1)
#pragma unroll
      for (int i = 0; i < 4; i++)
        if (i < st) v8[i] = fmaxf(v8[i], v8[i + st]);
    float mx = fmaxf(v8[0], __shfl_xor(v8[0], 32));
    float mn = fmaxf(mrun, mx);
    float corr = __expf(mrun - mn);
    mrun = mn;
#pragma unroll
    for (int i = 0; i < 16; i++) {
      sA[i] = __expf(sA[i] - mn);
      sB[i] = __expf(sB[i] - mn);
    }
    float s8[8];
#pragma unroll
    for (int i = 0; i < 8; i++)
      s8[i] = (sA[i] + sA[i + 8]) + (sB[i] + sB[i + 8]);
#pragma unroll
    for (int st = 4; st > 0; st >>= 1)
#pragma unroll
      for (int i = 0; i < 4; i++)
        if (i < st) s8[i] += s8[i + st];
    float rs = s8[0] + __shfl_xor(s8[0], 32);
    lrun = lrun * corr + rs;
    oA = oA * corr;
    oB = oB * corr;

    // ---- O^T += V^T P^T, per 32-key half ----
    // key(reg r, hi') = kb*32 + (r&3) + 8*(r>>2) + 4*hi'
    // cvt_pk pairs (2i,2i+1); permlane32_swap((c[j],c[j+2])) -> dword0/dword2 of frags
#pragma unroll
    for (int kb = 0; kb < 2; kb++) {
      const f32x16& sv = kb ? sB : sA;
      u32 c0 = cvtpk(sv[0], sv[1]),   c1 = cvtpk(sv[2], sv[3]);
      u32 c2 = cvtpk(sv[4], sv[5]),   c3 = cvtpk(sv[6], sv[7]);
      u32 c4 = cvtpk(sv[8], sv[9]),   c5 = cvtpk(sv[10], sv[11]);
      u32 c6 = cvtpk(sv[12], sv[13]), c7 = cvtpk(sv[14], sv[15]);
      plswap(c0, c2); plswap(c1, c3);   // -> frag for kc = kb*2 + 0
      plswap(c4, c6); plswap(c5, c7);   // -> frag for kc = kb*2 + 1
      u32x4 p0w; p0w[0] = c0; p0w[1] = c1; p0w[2] = c2; p0w[3] = c3;
      u32x4 p1w; p1w[0] = c4; p1w[1] = c5; p1w[2] = c6; p1w[3] = c7;
      bf16x8 pf0 = __builtin_bit_cast(bf16x8, p0w);
      bf16x8 pf1 = __builtin_bit_cast(bf16x8, p1w);
      int kc0 = kb * 2, kc1 = kb * 2 + 1;
      bf16x8 vA0 = *(const bf16x8*)(V + l31 * 128 + ((kc0 * 32 + hi * 16) ^ r7));
      bf16x8 vB0 = *(const bf16x8*)(V + (32 + l31) * 128 + ((kc0 * 32 + hi * 16) ^ r7));
      bf16x8 vA1 = *(const bf16x8*)(V + l31 * 128 + ((kc1 * 32 + hi * 16) ^ r7));
      bf16x8 vB1 = *(const bf16x8*)(V + (32 + l31) * 128 + ((kc1 * 32 + hi * 16) ^ r7));
      __builtin_amdgcn_s_setprio(1);
      oA = MFMA32(vA0, pf0, oA);
      oB = MFMA32(vB0, pf0, oB);
      oA = MFMA32(vA1, pf1, oA);
      oB = MFMA32(vB1, pf1, oB);
      __builtin_amdgcn_s_setprio(0);
    }

    __syncthreads();
    cur ^= 1;
  }
#undef STAGE

  // ---- finalize: O^T[d][q], lane q=l31 holds d = 32*db + 8*(r>>2) + 4*hi + (r&3) ----
  float inv = 1.0f / lrun;
  int b = blockIdx.y >> 3, h = blockIdx.y & 7;
  unsigned short* aorow = ao + ((size_t)b * 2048 + qrow) * 512 + h * 64;
#pragma unroll
  for (int g = 0; g < 4; g++) {
    u16x4 pa, pb;
#pragma unroll
    for (int j = 0; j < 4; j++) {
      pa[j] = f2bf(oA[g * 4 + j] * inv);
      pb[j] = f2bf(oB[g * 4 + j] * inv);
    }
    *(u16x4*)(aorow + g * 8 + hi * 4) = pa;
    *(u16x4*)(aorow + 32 + g * 8 + hi * 4) = pb;
  }
}

// ---------------- output projection: ao[8192][512] @ w_out -> d_out (f32) ----------------
__global__ __launch_bounds__(256, 2) void proj_kernel(char* __restrict__ ws,
                                                      float* __restrict__ dout) {
  __shared__ char lA[16384];
  __shared__ char lB[16384];
  int dir = blockIdx.z;
  const char* A = ws + (dir ? OFF_AO1 : OFF_AO0);
  const char* B = ws + (dir ? OFF_WO1 : OFF_WO0);
  int M0 = blockIdx.x * 128, N0 = blockIdx.y * 128;
  f32x4 zero = {0.f, 0.f, 0.f, 0.f};
  f32x4 acc[4][4];
#pragma unroll
  for (int mi = 0; mi < 4; mi++)
#pragma unroll
    for (int ni = 0; ni < 4; ni++) acc[mi][ni] = zero;
  gemm128_core(A, B, M0, N0, lA, lB, acc);

  int tid = threadIdx.x, w = tid >> 6, l = tid & 63;
  int wr = (w >> 1) * 64, wc = (w & 1) * 64;
  int l15 = l & 15, lg = l >> 4;
#pragma unroll
  for (int mi = 0; mi < 4; mi++) {
    int m = M0 + wr + mi * 16 + lg * 4;
    int bb = m >> 11, t = m & 2047;
    size_t orow = (size_t)bb * 4096 + (size_t)dir * 2048 + t;
#pragma unroll
    for (int ni = 0; ni < 4; ni++) {
      int n = N0 + wc + ni * 16 + l15;
#pragma unroll
      for (int r = 0; r < 4; r++) dout[(orow + r) * 512 + n] = acc[mi][ni][r];
    }
  }
}

// ---------------- launch ----------------
extern "C" void kernel_launch(void* const* d_in, const int* in_sizes, int n_in,
                              void* d_out, int out_size, void* d_ws, size_t ws_size,
                              hipStream_t stream) {
  const float* xi  = (const float*)d_in[0];
  const float* xt  = (const float*)d_in[1];
  const float* gi  = (const float*)d_in[2];
  const float* bi  = (const float*)d_in[3];
  const float* gt  = (const float*)d_in[4];
  const float* bt  = (const float*)d_in[5];
  const float* wqi = (const float*)d_in[6];
  const float* wqt = (const float*)d_in[7];
  const float* woi = (const float*)d_in[8];
  const float* wot = (const float*)d_in[9];
  char* ws = (char*)d_ws;
  float* out = (float*)d_out;

  wt_kernel<<<dim3(24, 8), 256, 0, stream>>>(wqi, (unsigned short*)(ws + OFF_WQ0), 512, 1536);
  wt_kernel<<<dim3(24, 8), 256, 0, stream>>>(wqt, (unsigned short*)(ws + OFF_WQ1), 512, 1536);
  wt_kernel<<<dim3(8, 8), 256, 0, stream>>>(woi, (unsigned short*)(ws + OFF_WO0), 512, 512);
  wt_kernel<<<dim3(8, 8), 256, 0, stream>>>(wot, (unsigned short*)(ws + OFF_WO1), 512, 512);
  ln_kernel<<<4096, 256, 0, stream>>>(xi, xt, gi, bi, gt, bt, ws);
  qkv_kernel<<<dim3(64, 12, 2), 256, 0, stream>>>(ws);
  attn_kernel<<<dim3(16, 32, 2), 256, 0, stream>>>(ws);
  proj_kernel<<<dim3(64, 4, 2), 256, 0, stream>>>(ws, out);
}

// Round 5
// 270.224 us; speedup vs baseline: 1.3427x; 1.0007x over previous
//
#include <hip/hip_runtime.h>
#include <stdint.h>

// ---------------- types ----------------
typedef short bf16x8 __attribute__((ext_vector_type(8)));
typedef float f32x4 __attribute__((ext_vector_type(4)));
typedef float f32x16 __attribute__((ext_vector_type(16)));
typedef unsigned short u16x4 __attribute__((ext_vector_type(4)));
typedef unsigned short u16x8 __attribute__((ext_vector_type(8)));
typedef unsigned int u32x4 __attribute__((ext_vector_type(4)));
typedef unsigned int u32;

#define MFMA16(a, b, c) __builtin_amdgcn_mfma_f32_16x16x32_bf16(a, b, c, 0, 0, 0)
#define MFMA32(a, b, c) __builtin_amdgcn_mfma_f32_32x32x16_bf16(a, b, c, 0, 0, 0)

// ---------------- workspace layout (byte offsets) ----------------
static constexpr size_t LN_BYTES   = 8192ull * 512 * 2;       // bf16 [8192][512]
static constexpr size_t WQKV_BYTES = 1536ull * 512 * 2;       // bf16 [1536][512] (N x K)
static constexpr size_t WOUT_BYTES = 512ull * 512 * 2;        // bf16 [512][512]  (N x K)
static constexpr size_t QKV_BYTES  = 4ull * 8 * 2048 * 64 * 2;

static constexpr size_t OFF_LN0 = 0;
static constexpr size_t OFF_LN1 = OFF_LN0 + LN_BYTES;
static constexpr size_t OFF_WQ0 = OFF_LN1 + LN_BYTES;
static constexpr size_t OFF_WQ1 = OFF_WQ0 + WQKV_BYTES;
static constexpr size_t OFF_WO0 = OFF_WQ1 + WQKV_BYTES;
static constexpr size_t OFF_WO1 = OFF_WO0 + WOUT_BYTES;
static constexpr size_t OFF_Q0  = OFF_WO1 + WOUT_BYTES;   // [b][h][n][d], pre-scaled by 0.125
static constexpr size_t OFF_K0  = OFF_Q0 + QKV_BYTES;     // [b][h][n][d]
static constexpr size_t OFF_VT0 = OFF_K0 + QKV_BYTES;     // [b][h][d][n]  (V transposed)
static constexpr size_t OFF_Q1  = OFF_VT0 + QKV_BYTES;
static constexpr size_t OFF_K1  = OFF_Q1 + QKV_BYTES;
static constexpr size_t OFF_VT1 = OFF_K1 + QKV_BYTES;
static constexpr size_t OFF_AO0 = OFF_LN0;                // t2i attn out, merged heads [8192][512]
static constexpr size_t OFF_AO1 = OFF_LN1;                // i2t attn out

// ---------------- helpers ----------------
__device__ __forceinline__ unsigned short f2bf(float f) {
  union { float f; unsigned int u; } v; v.f = f;
  unsigned int r = v.u + 0x7FFFu + ((v.u >> 16) & 1u);
  return (unsigned short)(r >> 16);
}

__device__ __forceinline__ void gload16(const void* g, void* l) {
  __builtin_amdgcn_global_load_lds(
      (const __attribute__((address_space(1))) void*)g,
      (__attribute__((address_space(3))) void*)l, 16, 0, 0);
}

__device__ __forceinline__ u32 cvtpk(float lo, float hi) {
  u32 d;
  asm("v_cvt_pk_bf16_f32 %0, %1, %2" : "=v"(d) : "v"(lo), "v"(hi));
  return d;
}

// (a,b) -> a' = {a.lo32lanes, b.lo32lanes}, b' = {a.hi32lanes, b.hi32lanes}
__device__ __forceinline__ void plswap(u32& a, u32& b) {
  asm("v_permlane32_swap_b32 %0, %1" : "+v"(a), "+v"(b));
}

__device__ __forceinline__ f32x16 zero16() {
  f32x16 z;
#pragma unroll
  for (int i = 0; i < 16; i++) z[i] = 0.0f;
  return z;
}

// ---------------- weight cast + transpose: w[K][N] f32 -> wt[N][K] bf16 ----------------
__global__ __launch_bounds__(256) void wt_kernel(const float* __restrict__ w,
                                                 unsigned short* __restrict__ wt,
                                                 int K, int N) {
  __shared__ float tile[64][65];
  int n0 = blockIdx.x * 64, k0 = blockIdx.y * 64;
  int t = threadIdx.x;
  int c = t & 63, rg = t >> 6;
#pragma unroll
  for (int i = 0; i < 16; i++) {
    int kk = i * 4 + rg;
    tile[kk][c] = w[(size_t)(k0 + kk) * N + n0 + c];
  }
  __syncthreads();
#pragma unroll
  for (int i = 0; i < 16; i++) {
    int nn = i * 4 + rg;
    wt[(size_t)(n0 + nn) * K + k0 + c] = f2bf(tile[c][nn]);
  }
}

// ---------------- layernorm (one wave per 512-wide row) ----------------
__global__ __launch_bounds__(256) void ln_kernel(
    const float* __restrict__ xi, const float* __restrict__ xt,
    const float* __restrict__ gi, const float* __restrict__ bi,
    const float* __restrict__ gt, const float* __restrict__ bt,
    char* __restrict__ ws) {
  int row = blockIdx.x * 4 + (threadIdx.x >> 6);
  int l = threadIdx.x & 63;
  const float *x, *g, *b; unsigned short* o; int r;
  if (row < 8192) { x = xi; g = gi; b = bi; o = (unsigned short*)(ws + OFF_LN0); r = row; }
  else            { x = xt; g = gt; b = bt; o = (unsigned short*)(ws + OFF_LN1); r = row - 8192; }
  const float4* xv = (const float4*)(x + (size_t)r * 512);
  float4 a0 = xv[l * 2], a1 = xv[l * 2 + 1];
  float s  = a0.x + a0.y + a0.z + a0.w + a1.x + a1.y + a1.z + a1.w;
  float ss = a0.x * a0.x + a0.y * a0.y + a0.z * a0.z + a0.w * a0.w +
             a1.x * a1.x + a1.y * a1.y + a1.z * a1.z + a1.w * a1.w;
#pragma unroll
  for (int m = 1; m < 64; m <<= 1) { s += __shfl_xor(s, m); ss += __shfl_xor(ss, m); }
  float mean = s * (1.0f / 512.0f);
  float var  = ss * (1.0f / 512.0f) - mean * mean;
  float rstd = rsqrtf(var + 1e-5f);
  const float4* gv = (const float4*)g;
  const float4* bv = (const float4*)b;
  float4 g0 = gv[l * 2], g1 = gv[l * 2 + 1], b0 = bv[l * 2], b1 = bv[l * 2 + 1];
  u16x8 ov;
  ov[0] = f2bf((a0.x - mean) * rstd * g0.x + b0.x);
  ov[1] = f2bf((a0.y - mean) * rstd * g0.y + b0.y);
  ov[2] = f2bf((a0.z - mean) * rstd * g0.z + b0.z);
  ov[3] = f2bf((a0.w - mean) * rstd * g0.w + b0.w);
  ov[4] = f2bf((a1.x - mean) * rstd * g1.x + b1.x);
  ov[5] = f2bf((a1.y - mean) * rstd * g1.y + b1.y);
  ov[6] = f2bf((a1.z - mean) * rstd * g1.z + b1.z);
  ov[7] = f2bf((a1.w - mean) * rstd * g1.w + b1.w);
  *(u16x8*)(o + (size_t)r * 512 + l * 8) = ov;
}

// ---------------- shared 128x128-tile GEMM core ----------------
__device__ __forceinline__ void gemm128_core(const char* __restrict__ A,
                                             const char* __restrict__ B,
                                             int M0, int N0,
                                             char* lA, char* lB, f32x4 acc[4][4]) {
  int tid = threadIdx.x, w = tid >> 6, l = tid & 63;
  int wr = (w >> 1) * 64, wc = (w & 1) * 64;
  int l15 = l & 15, lg = l >> 4;
  int rl = l >> 3;
  int cswz = ((l & 7) ^ rl) << 4;
#pragma unroll 1
  for (int kt = 0; kt < 512; kt += 64) {
#pragma unroll
    for (int i = 0; i < 4; i++) {
      int rr = (w * 4 + i) * 8 + rl;
      gload16(A + (size_t)(M0 + rr) * 1024 + kt * 2 + cswz, lA + (w * 4 + i) * 1024);
      gload16(B + (size_t)(N0 + rr) * 1024 + kt * 2 + cswz, lB + (w * 4 + i) * 1024);
    }
    __syncthreads();
#pragma unroll
    for (int kk = 0; kk < 2; kk++) {
      bf16x8 af[4], bfv[4];
#pragma unroll
      for (int mi = 0; mi < 4; mi++) {
        int row = wr + mi * 16 + l15;
        af[mi] = *(const bf16x8*)(lA + row * 128 + ((kk * 64 + lg * 16) ^ ((row & 7) << 4)));
      }
#pragma unroll
      for (int ni = 0; ni < 4; ni++) {
        int row = wc + ni * 16 + l15;
        bfv[ni] = *(const bf16x8*)(lB + row * 128 + ((kk * 64 + lg * 16) ^ ((row & 7) << 4)));
      }
#pragma unroll
      for (int mi = 0; mi < 4; mi++)
#pragma unroll
        for (int ni = 0; ni < 4; ni++)
          acc[mi][ni] = MFMA16(af[mi], bfv[ni], acc[mi][ni]);
    }
    __syncthreads();
  }
}

// ---------------- QKV GEMM: ln[8192][512] @ wqkv -> q/k/vt buffers ----------------
__global__ __launch_bounds__(256, 2) void qkv_kernel(char* __restrict__ ws) {
  __shared__ char lA[16384];
  __shared__ char lB[16384];
  int s = blockIdx.z;
  const char* A = ws + (s ? OFF_LN1 : OFF_LN0);
  const char* B = ws + (s ? OFF_WQ1 : OFF_WQ0);
  unsigned short* qb = (unsigned short*)(ws + (s ? OFF_Q1 : OFF_Q0));
  unsigned short* kb = (unsigned short*)(ws + (s ? OFF_K1 : OFF_K0));
  unsigned short* vb = (unsigned short*)(ws + (s ? OFF_VT1 : OFF_VT0));
  int M0 = blockIdx.x * 128, N0 = blockIdx.y * 128;
  f32x4 zero = {0.f, 0.f, 0.f, 0.f};
  f32x4 acc[4][4];
#pragma unroll
  for (int mi = 0; mi < 4; mi++)
#pragma unroll
    for (int ni = 0; ni < 4; ni++) acc[mi][ni] = zero;
  gemm128_core(A, B, M0, N0, lA, lB, acc);

  int tid = threadIdx.x, w = tid >> 6, l = tid & 63;
  int wr = (w >> 1) * 64, wc = (w & 1) * 64;
  int l15 = l & 15, lg = l >> 4;
  int which = N0 >> 9;  // 0=q, 1=k, 2=v
#pragma unroll
  for (int mi = 0; mi < 4; mi++) {
    int m = M0 + wr + mi * 16 + lg * 4;
    int bb = m >> 11, t = m & 2047;
#pragma unroll
    for (int ni = 0; ni < 4; ni++) {
      int n = N0 + wc + ni * 16 + l15;
      int h = (n >> 6) & 7, d = n & 63;
      if (which == 2) {
        u16x4 pk;
        pk[0] = f2bf(acc[mi][ni][0]);
        pk[1] = f2bf(acc[mi][ni][1]);
        pk[2] = f2bf(acc[mi][ni][2]);
        pk[3] = f2bf(acc[mi][ni][3]);
        *(u16x4*)(vb + ((size_t)(bb * 8 + h) * 64 + d) * 2048 + t) = pk;
      } else {
        unsigned short* dst = (which ? kb : qb) + ((size_t)(bb * 8 + h) * 2048 + t) * 64 + d;
        float sc = which ? 1.0f : 0.125f;  // q pre-scaled (exact pow2 in bf16)
#pragma unroll
        for (int r = 0; r < 4; r++) dst[(size_t)r * 64] = f2bf(acc[mi][ni][r] * sc);
      }
    }
  }
}

// ---------------- flash cross-attention, swapped-operand 32x32 (m214 structure) ----------------
// R2-validated numerics + ONE change: pin sA/sB to arch VGPRs after the QK MFMAs.
__global__ __launch_bounds__(256, 2) void attn_kernel(char* __restrict__ ws) {
  __shared__ char lK[2][8192];   // [key 64][d 64] bf16, XOR-swizzled
  __shared__ char lV[2][8192];   // [d 64][key 64] bf16, XOR-swizzled
  int dir = blockIdx.z;
  const char* kbh = ws + (dir ? OFF_K1 : OFF_K0) + (size_t)blockIdx.y * 2048 * 128;
  const char* vbh = ws + (dir ? OFF_VT1 : OFF_VT0) + (size_t)blockIdx.y * 2048 * 128;
  const char* qbh = ws + (dir ? OFF_Q0 : OFF_Q1) + (size_t)blockIdx.y * 2048 * 128;
  unsigned short* ao = (unsigned short*)(ws + (dir ? OFF_AO1 : OFF_AO0));
  int q0 = blockIdx.x * 128;

  int tid = threadIdx.x, w = tid >> 6, l = tid & 63;
  int l31 = l & 31, hi = l >> 5;
  int rl = l >> 3;
  int cswz = ((l & 7) ^ rl) << 4;
  int r7 = (l31 & 7) << 4;

  // Q fragments: qf[kc] = Q[q=qrow][d = 16*kc + 8*hi .. +7]  (pre-scaled by 0.125)
  int qrow = q0 + w * 32 + l31;
  bf16x8 qf[4];
#pragma unroll
  for (int kc = 0; kc < 4; kc++)
    qf[kc] = *(const bf16x8*)(qbh + (size_t)qrow * 128 + kc * 32 + hi * 16);

  f32x16 oA = zero16(), oB = zero16();
  float mrun = -3.0e38f, lrun = 0.f;

#define STAGE(buf, kt)                                                              \
  {                                                                                 \
    _Pragma("unroll")                                                               \
    for (int i = 0; i < 2; i++) {                                                   \
      int rr = (w * 2 + i) * 8 + rl;                                                \
      gload16(kbh + (size_t)((kt) * 64 + rr) * 128 + cswz, &lK[buf][(w * 2 + i) * 1024]); \
      gload16(vbh + (size_t)rr * 4096 + (kt) * 128 + cswz, &lV[buf][(w * 2 + i) * 1024]); \
    }                                                                               \
  }

  STAGE(0, 0);
  __syncthreads();

  int cur = 0;
#pragma unroll 1
  for (int kt = 0; kt < 32; kt++) {
    if (kt < 31) STAGE(cur ^ 1, kt + 1);

    const char* K = lK[cur];
    const char* V = lV[cur];

    // ---- S^T = K Q^T : sA = keys 0..31, sB = keys 32..63 of this tile ----
    f32x16 sA = zero16(), sB = zero16();
    __builtin_amdgcn_s_setprio(1);
#pragma unroll
    for (int kc = 0; kc < 4; kc++) {
      bf16x8 kfA = *(const bf16x8*)(K + l31 * 128 + ((kc * 32 + hi * 16) ^ r7));
      bf16x8 kfB = *(const bf16x8*)(K + (32 + l31) * 128 + ((kc * 32 + hi * 16) ^ r7));
      sA = MFMA32(kfA, qf[kc], sA);
      sB = MFMA32(kfB, qf[kc], sB);
    }
    __builtin_amdgcn_s_setprio(0);

    // pin score accumulators to arch VGPRs (softmax is VALU-hot; avoid accvgpr churn)
#pragma unroll
    for (int i = 0; i < 16; i++) {
      float ta = sA[i], tb = sB[i];
      asm volatile("" : "+v"(ta), "+v"(tb));
      sA[i] = ta; sB[i] = tb;
    }

    // ---- online softmax (lane-local q-row; keys split across hi halves) ----
    float v8[8];
#pragma unroll
    for (int i = 0; i < 8; i++)
      v8[i] = fmaxf(fmaxf(sA[i], sA[i + 8]), fmaxf(sB[i], sB[i + 8]));
#pragma unroll
    for (int st = 4; st > 0; st >>= 1)
#pragma unroll
      for (int i = 0; i < 4; i++)
        if (i < st) v8[i] = fmaxf(v8[i], v8[i + st]);
    float mx = fmaxf(v8[0], __shfl_xor(v8[0], 32));
    float mn = fmaxf(mrun, mx);
    float corr = __expf(mrun - mn);
    mrun = mn;
#pragma unroll
    for (int i = 0; i < 16; i++) {
      sA[i] = __expf(sA[i] - mn);
      sB[i] = __expf(sB[i] - mn);
    }
    float s8[8];
#pragma unroll
    for (int i = 0; i < 8; i++)
      s8[i] = (sA[i] + sA[i + 8]) + (sB[i] + sB[i + 8]);
#pragma unroll
    for (int st = 4; st > 0; st >>= 1)
#pragma unroll
      for (int i = 0; i < 4; i++)
        if (i < st) s8[i] += s8[i + st];
    float rs = s8[0] + __shfl_xor(s8[0], 32);
    lrun = lrun * corr + rs;
    oA = oA * corr;
    oB = oB * corr;

    // ---- O^T += V^T P^T, per 32-key half ----
#pragma unroll
    for (int kb = 0; kb < 2; kb++) {
      const f32x16& sv = kb ? sB : sA;
      u32 c0 = cvtpk(sv[0], sv[1]),   c1 = cvtpk(sv[2], sv[3]);
      u32 c2 = cvtpk(sv[4], sv[5]),   c3 = cvtpk(sv[6], sv[7]);
      u32 c4 = cvtpk(sv[8], sv[9]),   c5 = cvtpk(sv[10], sv[11]);
      u32 c6 = cvtpk(sv[12], sv[13]), c7 = cvtpk(sv[14], sv[15]);
      plswap(c0, c2); plswap(c1, c3);   // -> frag for kc = kb*2 + 0
      plswap(c4, c6); plswap(c5, c7);   // -> frag for kc = kb*2 + 1
      u32x4 p0w; p0w[0] = c0; p0w[1] = c1; p0w[2] = c2; p0w[3] = c3;
      u32x4 p1w; p1w[0] = c4; p1w[1] = c5; p1w[2] = c6; p1w[3] = c7;
      bf16x8 pf0 = __builtin_bit_cast(bf16x8, p0w);
      bf16x8 pf1 = __builtin_bit_cast(bf16x8, p1w);
      int kc0 = kb * 2, kc1 = kb * 2 + 1;
      bf16x8 vA0 = *(const bf16x8*)(V + l31 * 128 + ((kc0 * 32 + hi * 16) ^ r7));
      bf16x8 vB0 = *(const bf16x8*)(V + (32 + l31) * 128 + ((kc0 * 32 + hi * 16) ^ r7));
      bf16x8 vA1 = *(const bf16x8*)(V + l31 * 128 + ((kc1 * 32 + hi * 16) ^ r7));
      bf16x8 vB1 = *(const bf16x8*)(V + (32 + l31) * 128 + ((kc1 * 32 + hi * 16) ^ r7));
      __builtin_amdgcn_s_setprio(1);
      oA = MFMA32(vA0, pf0, oA);
      oB = MFMA32(vB0, pf0, oB);
      oA = MFMA32(vA1, pf1, oA);
      oB = MFMA32(vB1, pf1, oB);
      __builtin_amdgcn_s_setprio(0);
    }

    __syncthreads();
    cur ^= 1;
  }
#undef STAGE

  // ---- finalize: O^T[d][q], lane q=l31 ----
  float inv = 1.0f / lrun;
  int b = blockIdx.y >> 3, h = blockIdx.y & 7;
  unsigned short* aorow = ao + ((size_t)b * 2048 + qrow) * 512 + h * 64;
#pragma unroll
  for (int g = 0; g < 4; g++) {
    u16x4 pa, pb;
#pragma unroll
    for (int j = 0; j < 4; j++) {
      pa[j] = f2bf(oA[g * 4 + j] * inv);
      pb[j] = f2bf(oB[g * 4 + j] * inv);
    }
    *(u16x4*)(aorow + g * 8 + hi * 4) = pa;
    *(u16x4*)(aorow + 32 + g * 8 + hi * 4) = pb;
  }
}

// ---------------- output projection: ao[8192][512] @ w_out -> d_out (f32) ----------------
__global__ __launch_bounds__(256, 2) void proj_kernel(char* __restrict__ ws,
                                                      float* __restrict__ dout) {
  __shared__ char lA[16384];
  __shared__ char lB[16384];
  int dir = blockIdx.z;
  const char* A = ws + (dir ? OFF_AO1 : OFF_AO0);
  const char* B = ws + (dir ? OFF_WO1 : OFF_WO0);
  int M0 = blockIdx.x * 128, N0 = blockIdx.y * 128;
  f32x4 zero = {0.f, 0.f, 0.f, 0.f};
  f32x4 acc[4][4];
#pragma unroll
  for (int mi = 0; mi < 4; mi++)
#pragma unroll
    for (int ni = 0; ni < 4; ni++) acc[mi][ni] = zero;
  gemm128_core(A, B, M0, N0, lA, lB, acc);

  int tid = threadIdx.x, w = tid >> 6, l = tid & 63;
  int wr = (w >> 1) * 64, wc = (w & 1) * 64;
  int l15 = l & 15, lg = l >> 4;
#pragma unroll
  for (int mi = 0; mi < 4; mi++) {
    int m = M0 + wr + mi * 16 + lg * 4;
    int bb = m >> 11, t = m & 2047;
    size_t orow = (size_t)bb * 4096 + (size_t)dir * 2048 + t;
#pragma unroll
    for (int ni = 0; ni < 4; ni++) {
      int n = N0 + wc + ni * 16 + l15;
#pragma unroll
      for (int r = 0; r < 4; r++) dout[(orow + r) * 512 + n] = acc[mi][ni][r];
    }
  }
}

// ---------------- launch ----------------
extern "C" void kernel_launch(void* const* d_in, const int* in_sizes, int n_in,
                              void* d_out, int out_size, void* d_ws, size_t ws_size,
                              hipStream_t stream) {
  const float* xi  = (const float*)d_in[0];
  const float* xt  = (const float*)d_in[1];
  const float* gi  = (const float*)d_in[2];
  const float* bi  = (const float*)d_in[3];
  const float* gt  = (const float*)d_in[4];
  const float* bt  = (const float*)d_in[5];
  const float* wqi = (const float*)d_in[6];
  const float* wqt = (const float*)d_in[7];
  const float* woi = (const float*)d_in[8];
  const float* wot = (const float*)d_in[9];
  char* ws = (char*)d_ws;
  float* out = (float*)d_out;

  wt_kernel<<<dim3(24, 8), 256, 0, stream>>>(wqi, (unsigned short*)(ws + OFF_WQ0), 512, 1536);
  wt_kernel<<<dim3(24, 8), 256, 0, stream>>>(wqt, (unsigned short*)(ws + OFF_WQ1), 512, 1536);
  wt_kernel<<<dim3(8, 8), 256, 0, stream>>>(woi, (unsigned short*)(ws + OFF_WO0), 512, 512);
  wt_kernel<<<dim3(8, 8), 256, 0, stream>>>(wot, (unsigned short*)(ws + OFF_WO1), 512, 512);
  ln_kernel<<<4096, 256, 0, stream>>>(xi, xt, gi, bi, gt, bt, ws);
  qkv_kernel<<<dim3(64, 12, 2), 256, 0, stream>>>(ws);
  attn_kernel<<<dim3(16, 32, 2), 256, 0, stream>>>(ws);
  proj_kernel<<<dim3(64, 4, 2), 256, 0, stream>>>(ws, out);
}

// Round 6
// 262.597 us; speedup vs baseline: 1.3817x; 1.0290x over previous
//
#include <hip/hip_runtime.h>
#include <stdint.h>

// ---------------- types ----------------
typedef short bf16x8 __attribute__((ext_vector_type(8)));
typedef float f32x4 __attribute__((ext_vector_type(4)));
typedef float f32x16 __attribute__((ext_vector_type(16)));
typedef unsigned short u16x4 __attribute__((ext_vector_type(4)));
typedef unsigned short u16x8 __attribute__((ext_vector_type(8)));
typedef unsigned int u32x4 __attribute__((ext_vector_type(4)));
typedef unsigned int u32;

#define MFMA16(a, b, c) __builtin_amdgcn_mfma_f32_16x16x32_bf16(a, b, c, 0, 0, 0)
#define MFMA32(a, b, c) __builtin_amdgcn_mfma_f32_32x32x16_bf16(a, b, c, 0, 0, 0)

// ---------------- workspace layout (byte offsets) ----------------
static constexpr size_t LN_BYTES   = 8192ull * 512 * 2;       // bf16 [8192][512]
static constexpr size_t WQKV_BYTES = 1536ull * 512 * 2;       // bf16 [1536][512] (N x K)
static constexpr size_t WOUT_BYTES = 512ull * 512 * 2;        // bf16 [512][512]  (N x K)
static constexpr size_t QKV_BYTES  = 4ull * 8 * 2048 * 64 * 2;

static constexpr size_t OFF_LN0 = 0;
static constexpr size_t OFF_LN1 = OFF_LN0 + LN_BYTES;
static constexpr size_t OFF_WQ0 = OFF_LN1 + LN_BYTES;
static constexpr size_t OFF_WQ1 = OFF_WQ0 + WQKV_BYTES;
static constexpr size_t OFF_WO0 = OFF_WQ1 + WQKV_BYTES;
static constexpr size_t OFF_WO1 = OFF_WO0 + WOUT_BYTES;
static constexpr size_t OFF_Q0  = OFF_WO1 + WOUT_BYTES;   // [b][h][n][d], pre-scaled by 0.125*log2e
static constexpr size_t OFF_K0  = OFF_Q0 + QKV_BYTES;     // [b][h][n][d]
static constexpr size_t OFF_VT0 = OFF_K0 + QKV_BYTES;     // [b][h][d][n]  (V transposed)
static constexpr size_t OFF_Q1  = OFF_VT0 + QKV_BYTES;
static constexpr size_t OFF_K1  = OFF_Q1 + QKV_BYTES;
static constexpr size_t OFF_VT1 = OFF_K1 + QKV_BYTES;
static constexpr size_t OFF_AO0 = OFF_LN0;                // t2i attn out, merged heads [8192][512]
static constexpr size_t OFF_AO1 = OFF_LN1;                // i2t attn out

// ---------------- helpers ----------------
__device__ __forceinline__ unsigned short f2bf(float f) {
  union { float f; unsigned int u; } v; v.f = f;
  unsigned int r = v.u + 0x7FFFu + ((v.u >> 16) & 1u);
  return (unsigned short)(r >> 16);
}

__device__ __forceinline__ void gload16(const void* g, void* l) {
  __builtin_amdgcn_global_load_lds(
      (const __attribute__((address_space(1))) void*)g,
      (__attribute__((address_space(3))) void*)l, 16, 0, 0);
}

__device__ __forceinline__ u32 cvtpk(float lo, float hi) {
  u32 d;
  asm("v_cvt_pk_bf16_f32 %0, %1, %2" : "=v"(d) : "v"(lo), "v"(hi));
  return d;
}

// (a,b) -> a' = {a.lo32lanes, b.lo32lanes}, b' = {a.hi32lanes, b.hi32lanes}
// NOTE: only safe when a and b are DISTINCT values (regalloc may coalesce equal
// values into one register, turning the swap into a self-swap — R3 bug).
__device__ __forceinline__ void plswap(u32& a, u32& b) {
  asm("v_permlane32_swap_b32 %0, %1" : "+v"(a), "+v"(b));
}

__device__ __forceinline__ f32x16 zero16() {
  f32x16 z;
#pragma unroll
  for (int i = 0; i < 16; i++) z[i] = 0.0f;
  return z;
}

// ---------------- weight cast + transpose: w[K][N] f32 -> wt[N][K] bf16 ----------------
__global__ __launch_bounds__(256) void wt_kernel(const float* __restrict__ w,
                                                 unsigned short* __restrict__ wt,
                                                 int K, int N) {
  __shared__ float tile[64][65];
  int n0 = blockIdx.x * 64, k0 = blockIdx.y * 64;
  int t = threadIdx.x;
  int c = t & 63, rg = t >> 6;
#pragma unroll
  for (int i = 0; i < 16; i++) {
    int kk = i * 4 + rg;
    tile[kk][c] = w[(size_t)(k0 + kk) * N + n0 + c];
  }
  __syncthreads();
#pragma unroll
  for (int i = 0; i < 16; i++) {
    int nn = i * 4 + rg;
    wt[(size_t)(n0 + nn) * K + k0 + c] = f2bf(tile[c][nn]);
  }
}

// ---------------- layernorm (one wave per 512-wide row) ----------------
__global__ __launch_bounds__(256) void ln_kernel(
    const float* __restrict__ xi, const float* __restrict__ xt,
    const float* __restrict__ gi, const float* __restrict__ bi,
    const float* __restrict__ gt, const float* __restrict__ bt,
    char* __restrict__ ws) {
  int row = blockIdx.x * 4 + (threadIdx.x >> 6);
  int l = threadIdx.x & 63;
  const float *x, *g, *b; unsigned short* o; int r;
  if (row < 8192) { x = xi; g = gi; b = bi; o = (unsigned short*)(ws + OFF_LN0); r = row; }
  else            { x = xt; g = gt; b = bt; o = (unsigned short*)(ws + OFF_LN1); r = row - 8192; }
  const float4* xv = (const float4*)(x + (size_t)r * 512);
  float4 a0 = xv[l * 2], a1 = xv[l * 2 + 1];
  float s  = a0.x + a0.y + a0.z + a0.w + a1.x + a1.y + a1.z + a1.w;
  float ss = a0.x * a0.x + a0.y * a0.y + a0.z * a0.z + a0.w * a0.w +
             a1.x * a1.x + a1.y * a1.y + a1.z * a1.z + a1.w * a1.w;
#pragma unroll
  for (int m = 1; m < 64; m <<= 1) { s += __shfl_xor(s, m); ss += __shfl_xor(ss, m); }
  float mean = s * (1.0f / 512.0f);
  float var  = ss * (1.0f / 512.0f) - mean * mean;
  float rstd = rsqrtf(var + 1e-5f);
  const float4* gv = (const float4*)g;
  const float4* bv = (const float4*)b;
  float4 g0 = gv[l * 2], g1 = gv[l * 2 + 1], b0 = bv[l * 2], b1 = bv[l * 2 + 1];
  u16x8 ov;
  ov[0] = f2bf((a0.x - mean) * rstd * g0.x + b0.x);
  ov[1] = f2bf((a0.y - mean) * rstd * g0.y + b0.y);
  ov[2] = f2bf((a0.z - mean) * rstd * g0.z + b0.z);
  ov[3] = f2bf((a0.w - mean) * rstd * g0.w + b0.w);
  ov[4] = f2bf((a1.x - mean) * rstd * g1.x + b1.x);
  ov[5] = f2bf((a1.y - mean) * rstd * g1.y + b1.y);
  ov[6] = f2bf((a1.z - mean) * rstd * g1.z + b1.z);
  ov[7] = f2bf((a1.w - mean) * rstd * g1.w + b1.w);
  *(u16x8*)(o + (size_t)r * 512 + l * 8) = ov;
}

// ---------------- shared 128x128-tile GEMM core ----------------
__device__ __forceinline__ void gemm128_core(const char* __restrict__ A,
                                             const char* __restrict__ B,
                                             int M0, int N0,
                                             char* lA, char* lB, f32x4 acc[4][4]) {
  int tid = threadIdx.x, w = tid >> 6, l = tid & 63;
  int wr = (w >> 1) * 64, wc = (w & 1) * 64;
  int l15 = l & 15, lg = l >> 4;
  int rl = l >> 3;
  int cswz = ((l & 7) ^ rl) << 4;
#pragma unroll 1
  for (int kt = 0; kt < 512; kt += 64) {
#pragma unroll
    for (int i = 0; i < 4; i++) {
      int rr = (w * 4 + i) * 8 + rl;
      gload16(A + (size_t)(M0 + rr) * 1024 + kt * 2 + cswz, lA + (w * 4 + i) * 1024);
      gload16(B + (size_t)(N0 + rr) * 1024 + kt * 2 + cswz, lB + (w * 4 + i) * 1024);
    }
    __syncthreads();
#pragma unroll
    for (int kk = 0; kk < 2; kk++) {
      bf16x8 af[4], bfv[4];
#pragma unroll
      for (int mi = 0; mi < 4; mi++) {
        int row = wr + mi * 16 + l15;
        af[mi] = *(const bf16x8*)(lA + row * 128 + ((kk * 64 + lg * 16) ^ ((row & 7) << 4)));
      }
#pragma unroll
      for (int ni = 0; ni < 4; ni++) {
        int row = wc + ni * 16 + l15;
        bfv[ni] = *(const bf16x8*)(lB + row * 128 + ((kk * 64 + lg * 16) ^ ((row & 7) << 4)));
      }
#pragma unroll
      for (int mi = 0; mi < 4; mi++)
#pragma unroll
        for (int ni = 0; ni < 4; ni++)
          acc[mi][ni] = MFMA16(af[mi], bfv[ni], acc[mi][ni]);
    }
    __syncthreads();
  }
}

// ---------------- QKV GEMM: ln[8192][512] @ wqkv -> q/k/vt buffers ----------------
__global__ __launch_bounds__(256, 2) void qkv_kernel(char* __restrict__ ws) {
  __shared__ char lA[16384];
  __shared__ char lB[16384];
  int s = blockIdx.z;
  const char* A = ws + (s ? OFF_LN1 : OFF_LN0);
  const char* B = ws + (s ? OFF_WQ1 : OFF_WQ0);
  unsigned short* qb = (unsigned short*)(ws + (s ? OFF_Q1 : OFF_Q0));
  unsigned short* kb = (unsigned short*)(ws + (s ? OFF_K1 : OFF_K0));
  unsigned short* vb = (unsigned short*)(ws + (s ? OFF_VT1 : OFF_VT0));
  int M0 = blockIdx.x * 128, N0 = blockIdx.y * 128;
  f32x4 zero = {0.f, 0.f, 0.f, 0.f};
  f32x4 acc[4][4];
#pragma unroll
  for (int mi = 0; mi < 4; mi++)
#pragma unroll
    for (int ni = 0; ni < 4; ni++) acc[mi][ni] = zero;
  gemm128_core(A, B, M0, N0, lA, lB, acc);

  int tid = threadIdx.x, w = tid >> 6, l = tid & 63;
  int wr = (w >> 1) * 64, wc = (w & 1) * 64;
  int l15 = l & 15, lg = l >> 4;
  int which = N0 >> 9;  // 0=q, 1=k, 2=v
#pragma unroll
  for (int mi = 0; mi < 4; mi++) {
    int m = M0 + wr + mi * 16 + lg * 4;
    int bb = m >> 11, t = m & 2047;
#pragma unroll
    for (int ni = 0; ni < 4; ni++) {
      int n = N0 + wc + ni * 16 + l15;
      int h = (n >> 6) & 7, d = n & 63;
      if (which == 2) {
        u16x4 pk;
        pk[0] = f2bf(acc[mi][ni][0]);
        pk[1] = f2bf(acc[mi][ni][1]);
        pk[2] = f2bf(acc[mi][ni][2]);
        pk[3] = f2bf(acc[mi][ni][3]);
        *(u16x4*)(vb + ((size_t)(bb * 8 + h) * 64 + d) * 2048 + t) = pk;
      } else {
        unsigned short* dst = (which ? kb : qb) + ((size_t)(bb * 8 + h) * 2048 + t) * 64 + d;
        // q pre-scaled by SCALE*log2(e) so softmax can use exp2 directly
        float sc = which ? 1.0f : 0.18033688011112042f;
#pragma unroll
        for (int r = 0; r < 4; r++) dst[(size_t)r * 64] = f2bf(acc[mi][ni][r] * sc);
      }
    }
  }
}

// ---------------- flash cross-attention, swapped-operand 32x32 (m214 structure) ----------------
// R5-validated base + {defer-max, exp2-direct, ones-MFMA row-sum}; cross-half max
// via __shfl_xor (plswap self-swap hazard, see plswap comment).
__global__ __launch_bounds__(256, 2) void attn_kernel(char* __restrict__ ws) {
  __shared__ char lK[2][8192];   // [key 64][d 64] bf16, XOR-swizzled
  __shared__ char lV[2][8192];   // [d 64][key 64] bf16, XOR-swizzled
  int dir = blockIdx.z;
  const char* kbh = ws + (dir ? OFF_K1 : OFF_K0) + (size_t)blockIdx.y * 2048 * 128;
  const char* vbh = ws + (dir ? OFF_VT1 : OFF_VT0) + (size_t)blockIdx.y * 2048 * 128;
  const char* qbh = ws + (dir ? OFF_Q0 : OFF_Q1) + (size_t)blockIdx.y * 2048 * 128;
  unsigned short* ao = (unsigned short*)(ws + (dir ? OFF_AO1 : OFF_AO0));
  int q0 = blockIdx.x * 128;

  int tid = threadIdx.x, w = tid >> 6, l = tid & 63;
  int l31 = l & 31, hi = l >> 5;
  int rl = l >> 3;
  int cswz = ((l & 7) ^ rl) << 4;
  int r7 = (l31 & 7) << 4;

  // Q fragments: qf[kc] = Q[q=qrow][d = 16*kc + 8*hi .. +7]  (pre-scaled)
  int qrow = q0 + w * 32 + l31;
  bf16x8 qf[4];
#pragma unroll
  for (int kc = 0; kc < 4; kc++)
    qf[kc] = *(const bf16x8*)(qbh + (size_t)qrow * 128 + kc * 32 + hi * 16);

  bf16x8 ones;
#pragma unroll
  for (int i = 0; i < 8; i++) ones[i] = (short)0x3F80;  // bf16 1.0

  f32x16 oA = zero16(), oB = zero16(), lac = zero16();
  float mrun = -3.0e38f;

#define STAGE(buf, kt)                                                              \
  {                                                                                 \
    _Pragma("unroll")                                                               \
    for (int i = 0; i < 2; i++) {                                                   \
      int rr = (w * 2 + i) * 8 + rl;                                                \
      gload16(kbh + (size_t)((kt) * 64 + rr) * 128 + cswz, &lK[buf][(w * 2 + i) * 1024]); \
      gload16(vbh + (size_t)rr * 4096 + (kt) * 128 + cswz, &lV[buf][(w * 2 + i) * 1024]); \
    }                                                                               \
  }

  STAGE(0, 0);
  __syncthreads();

  int cur = 0;
#pragma unroll 1
  for (int kt = 0; kt < 32; kt++) {
    if (kt < 31) STAGE(cur ^ 1, kt + 1);

    const char* K = lK[cur];
    const char* V = lV[cur];

    // ---- S^T = K Q^T : sA = keys 0..31, sB = keys 32..63 (log2-domain scores) ----
    f32x16 sA = zero16(), sB = zero16();
    __builtin_amdgcn_s_setprio(1);
#pragma unroll
    for (int kc = 0; kc < 4; kc++) {
      bf16x8 kfA = *(const bf16x8*)(K + l31 * 128 + ((kc * 32 + hi * 16) ^ r7));
      bf16x8 kfB = *(const bf16x8*)(K + (32 + l31) * 128 + ((kc * 32 + hi * 16) ^ r7));
      sA = MFMA32(kfA, qf[kc], sA);
      sB = MFMA32(kfB, qf[kc], sB);
    }
    __builtin_amdgcn_s_setprio(0);

    // pin score accumulators to arch VGPRs (inert per R5; kept for diff minimality)
#pragma unroll
    for (int i = 0; i < 16; i++) {
      float ta = sA[i], tb = sB[i];
      asm volatile("" : "+v"(ta), "+v"(tb));
      sA[i] = ta; sB[i] = tb;
    }

    // ---- online softmax (lane-local q-row; keys split across hi halves) ----
    float v8[8];
#pragma unroll
    for (int i = 0; i < 8; i++)
      v8[i] = fmaxf(fmaxf(sA[i], sA[i + 8]), fmaxf(sB[i], sB[i + 8]));
#pragma unroll
    for (int st = 4; st > 0; st >>= 1)
#pragma unroll
      for (int i = 0; i < 4; i++)
        if (i < st) v8[i] = fmaxf(v8[i], v8[i + st]);
    float mx = fmaxf(v8[0], __shfl_xor(v8[0], 32));

    // defer-max (T13): rescale only if some lane's max grew past THR (log2 units)
    if (__any(mx > mrun + 11.0f)) {
      float mn = fmaxf(mrun, mx);
      float corr = __builtin_amdgcn_exp2f(mrun - mn);
      mrun = mn;
#pragma unroll
      for (int i = 0; i < 16; i++) { oA[i] *= corr; oB[i] *= corr; lac[i] *= corr; }
    }
#pragma unroll
    for (int i = 0; i < 16; i++) {
      sA[i] = __builtin_amdgcn_exp2f(sA[i] - mrun);
      sB[i] = __builtin_amdgcn_exp2f(sB[i] - mrun);
    }

    // ---- O^T += V^T P^T ; row-sums via ones-MFMA (lac) ----
#pragma unroll
    for (int kb = 0; kb < 2; kb++) {
      const f32x16& sv = kb ? sB : sA;
      u32 c0 = cvtpk(sv[0], sv[1]),   c1 = cvtpk(sv[2], sv[3]);
      u32 c2 = cvtpk(sv[4], sv[5]),   c3 = cvtpk(sv[6], sv[7]);
      u32 c4 = cvtpk(sv[8], sv[9]),   c5 = cvtpk(sv[10], sv[11]);
      u32 c6 = cvtpk(sv[12], sv[13]), c7 = cvtpk(sv[14], sv[15]);
      plswap(c0, c2); plswap(c1, c3);   // -> frag for kc = kb*2 + 0  (distinct values: safe)
      plswap(c4, c6); plswap(c5, c7);   // -> frag for kc = kb*2 + 1
      u32x4 p0w; p0w[0] = c0; p0w[1] = c1; p0w[2] = c2; p0w[3] = c3;
      u32x4 p1w; p1w[0] = c4; p1w[1] = c5; p1w[2] = c6; p1w[3] = c7;
      bf16x8 pf0 = __builtin_bit_cast(bf16x8, p0w);
      bf16x8 pf1 = __builtin_bit_cast(bf16x8, p1w);
      int kc0 = kb * 2, kc1 = kb * 2 + 1;
      bf16x8 vA0 = *(const bf16x8*)(V + l31 * 128 + ((kc0 * 32 + hi * 16) ^ r7));
      bf16x8 vB0 = *(const bf16x8*)(V + (32 + l31) * 128 + ((kc0 * 32 + hi * 16) ^ r7));
      bf16x8 vA1 = *(const bf16x8*)(V + l31 * 128 + ((kc1 * 32 + hi * 16) ^ r7));
      bf16x8 vB1 = *(const bf16x8*)(V + (32 + l31) * 128 + ((kc1 * 32 + hi * 16) ^ r7));
      __builtin_amdgcn_s_setprio(1);
      oA = MFMA32(vA0, pf0, oA);
      oB = MFMA32(vB0, pf0, oB);
      lac = MFMA32(ones, pf0, lac);
      oA = MFMA32(vA1, pf1, oA);
      oB = MFMA32(vB1, pf1, oB);
      lac = MFMA32(ones, pf1, lac);
      __builtin_amdgcn_s_setprio(0);
    }

    __syncthreads();
    cur ^= 1;
  }
#undef STAGE

  // ---- finalize: O^T[d][q], lane q=l31; lac rows all hold the row-sum ----
  float inv = 1.0f / lac[0];
  int b = blockIdx.y >> 3, h = blockIdx.y & 7;
  unsigned short* aorow = ao + ((size_t)b * 2048 + qrow) * 512 + h * 64;
#pragma unroll
  for (int g = 0; g < 4; g++) {
    u16x4 pa, pb;
#pragma unroll
    for (int j = 0; j < 4; j++) {
      pa[j] = f2bf(oA[g * 4 + j] * inv);
      pb[j] = f2bf(oB[g * 4 + j] * inv);
    }
    *(u16x4*)(aorow + g * 8 + hi * 4) = pa;
    *(u16x4*)(aorow + 32 + g * 8 + hi * 4) = pb;
  }
}

// ---------------- output projection: ao[8192][512] @ w_out -> d_out (f32) ----------------
__global__ __launch_bounds__(256, 2) void proj_kernel(char* __restrict__ ws,
                                                      float* __restrict__ dout) {
  __shared__ char lA[16384];
  __shared__ char lB[16384];
  int dir = blockIdx.z;
  const char* A = ws + (dir ? OFF_AO1 : OFF_AO0);
  const char* B = ws + (dir ? OFF_WO1 : OFF_WO0);
  int M0 = blockIdx.x * 128, N0 = blockIdx.y * 128;
  f32x4 zero = {0.f, 0.f, 0.f, 0.f};
  f32x4 acc[4][4];
#pragma unroll
  for (int mi = 0; mi < 4; mi++)
#pragma unroll
    for (int ni = 0; ni < 4; ni++) acc[mi][ni] = zero;
  gemm128_core(A, B, M0, N0, lA, lB, acc);

  int tid = threadIdx.x, w = tid >> 6, l = tid & 63;
  int wr = (w >> 1) * 64, wc = (w & 1) * 64;
  int l15 = l & 15, lg = l >> 4;
#pragma unroll
  for (int mi = 0; mi < 4; mi++) {
    int m = M0 + wr + mi * 16 + lg * 4;
    int bb = m >> 11, t = m & 2047;
    size_t orow = (size_t)bb * 4096 + (size_t)dir * 2048 + t;
#pragma unroll
    for (int ni = 0; ni < 4; ni++) {
      int n = N0 + wc + ni * 16 + l15;
#pragma unroll
      for (int r = 0; r < 4; r++) dout[(orow + r) * 512 + n] = acc[mi][ni][r];
    }
  }
}

// ---------------- launch ----------------
extern "C" void kernel_launch(void* const* d_in, const int* in_sizes, int n_in,
                              void* d_out, int out_size, void* d_ws, size_t ws_size,
                              hipStream_t stream) {
  const float* xi  = (const float*)d_in[0];
  const float* xt  = (const float*)d_in[1];
  const float* gi  = (const float*)d_in[2];
  const float* bi  = (const float*)d_in[3];
  const float* gt  = (const float*)d_in[4];
  const float* bt  = (const float*)d_in[5];
  const float* wqi = (const float*)d_in[6];
  const float* wqt = (const float*)d_in[7];
  const float* woi = (const float*)d_in[8];
  const float* wot = (const float*)d_in[9];
  char* ws = (char*)d_ws;
  float* out = (float*)d_out;

  wt_kernel<<<dim3(24, 8), 256, 0, stream>>>(wqi, (unsigned short*)(ws + OFF_WQ0), 512, 1536);
  wt_kernel<<<dim3(24, 8), 256, 0, stream>>>(wqt, (unsigned short*)(ws + OFF_WQ1), 512, 1536);
  wt_kernel<<<dim3(8, 8), 256, 0, stream>>>(woi, (unsigned short*)(ws + OFF_WO0), 512, 512);
  wt_kernel<<<dim3(8, 8), 256, 0, stream>>>(wot, (unsigned short*)(ws + OFF_WO1), 512, 512);
  ln_kernel<<<4096, 256, 0, stream>>>(xi, xt, gi, bi, gt, bt, ws);
  qkv_kernel<<<dim3(64, 12, 2), 256, 0, stream>>>(ws);
  attn_kernel<<<dim3(16, 32, 2), 256, 0, stream>>>(ws);
  proj_kernel<<<dim3(64, 4, 2), 256, 0, stream>>>(ws, out);
}